// Round 1
// baseline (881.135 us; speedup 1.0000x reference)
//
#include <hip/hip_runtime.h>

// PointNet on MI355X.
// B=32, P=2048, K=16, NHID=128, NCLS=10.
// Pipeline:
//   K1 knn      : brute-force d2 + wave-level iterative top-16 (u64 keys, exact top_k tie-break)
//   K2 layer1   : msg = relu(pos_j*(A+B) + (b1a - pos_p*B)); v = msg @ W1b (MFMA); h1 = relu(max_k v + b1b)
//                 h1 stored bf16 with pos appended in cols 128..130 (cols 131..159 zero)
//   K3 midgemm  : u2' = [h1|pos|0] @ W2a(all 131 rows) + b2a   (so u2' = h@W2a_top + b2a + pos*R)
//   K4 layer2   : msg = relu(u2'[j] - pos_p*R); v = msg @ W2b (MFMA); h2 = relu(max_k v + b2b);
//                 fused global max pool via LDS atomicMax -> global atomicMax (relu>=0 so int-max works)
//   K5 cls      : out = g @ Wc + bc  (fp32)
// MFMA layouts per verified m89/m97 mappings:
//   A[m][k]: m=lane&15, k=quad*8+j ; B[k][n]: n=lane&15, k=quad*8+j ; D[row][col]: col=lane&15, row=quad*4+reg

typedef __bf16 bf16x8 __attribute__((ext_vector_type(8)));
typedef float  f32x4  __attribute__((ext_vector_type(4)));

#define LDSA __attribute__((aligned(16)))

// ---------------------------------------------------------------- K1: KNN
__global__ __launch_bounds__(256) void knn_kernel(const float* __restrict__ pos,
                                                  int* __restrict__ nbr) {
  __shared__ LDSA float4 P4[2048];  // {x,y,z,|p|^2} per node of this batch
  const int blk = blockIdx.x;
  const int b = blk >> 5;                 // 32 blocks per batch
  const int p0 = (blk & 31) * 64;         // 64 points per block
  const int tid = threadIdx.x;
  const size_t bbase = (size_t)b * 2048;
  for (int idx = tid; idx < 2048; idx += 256) {
    const float* pp = pos + (bbase + idx) * 3;
    float x = pp[0], y = pp[1], z = pp[2];
    float sq = fmaf(z, z, fmaf(y, y, x * x));
    P4[idx] = make_float4(x, y, z, sq);
  }
  __syncthreads();
  const int wave = tid >> 6, lane = tid & 63;
  for (int it = 0; it < 16; ++it) {
    const int pl = p0 + wave * 16 + it;
    const float4 P = P4[pl];
    unsigned long long key[32];
#pragma unroll
    for (int i = 0; i < 32; ++i) {
      int c = lane + 64 * i;
      float4 Q = P4[c];
      float dot = fmaf(P.z, Q.z, fmaf(P.y, Q.y, P.x * Q.x));
      float d2 = (P.w + Q.w) - 2.0f * dot;     // matches sq_p + sq_q - 2*einsum
      unsigned u = __float_as_uint(d2);
      u = (u >> 31) ? ~u : (u | 0x80000000u);  // monotone float->uint (handles tiny negatives)
      key[i] = ((unsigned long long)u << 32) | (unsigned)c;  // ties broken by smaller index
    }
    unsigned long long prev = 0;  // all keys > 0
    for (int r = 0; r < 16; ++r) {
      unsigned long long best = ~0ull;
#pragma unroll
      for (int i = 0; i < 32; ++i) {
        unsigned long long k = key[i];
        bool ok = (k > prev) & (k < best);
        best = ok ? k : best;
      }
#pragma unroll
      for (int off = 32; off >= 1; off >>= 1) {
        unsigned long long o = __shfl_xor(best, off);
        best = (o < best) ? o : best;
      }
      if (lane == r) nbr[((size_t)b * 2048 + pl) * 16 + r] = (int)(best & 2047ull);
      prev = best;
    }
  }
}

// ---------------------------------------------------------------- K2: layer 1
__global__ __launch_bounds__(256, 2) void layer1_kernel(
    const float* __restrict__ pos, const int* __restrict__ nbr,
    const float* __restrict__ W1a, const float* __restrict__ b1a,
    const float* __restrict__ W1b, const float* __restrict__ b1b,
    __bf16* __restrict__ h1e) {
  __shared__ LDSA __bf16 Wbt[128 * 136];       // W1b^T [n][k], row pad to 136
  __shared__ LDSA __bf16 mt[4][16 * 136];      // per-wave message tile [k-neigh][c]
  __shared__ LDSA float S0[128], S1[128], S2[128];   // rows of (A+B)
  __shared__ LDSA float Br0[128], Br1[128], Br2[128];// rows of B (rel part of W1a)
  __shared__ LDSA float b1aL[128], b1bL[128];
  __shared__ LDSA float base2[4][128];
  const int tid = threadIdx.x;
  for (int idx = tid; idx < 16384; idx += 256) {
    int k = idx >> 7, n = idx & 127;
    Wbt[n * 136 + k] = (__bf16)W1b[idx];
  }
  if (tid < 128) {
    int c = tid;
    float a0 = W1a[c], a1 = W1a[128 + c], a2 = W1a[256 + c];
    float r0 = W1a[384 + c], r1 = W1a[512 + c], r2 = W1a[640 + c];
    S0[c] = a0 + r0; S1[c] = a1 + r1; S2[c] = a2 + r2;
    Br0[c] = r0; Br1[c] = r1; Br2[c] = r2;
    b1aL[c] = b1a[c]; b1bL[c] = b1b[c];
  }
  __syncthreads();
  const int wave = tid >> 6, lane = tid & 63;
  const int q = lane >> 4, c15 = lane & 15;
  const int kk = lane >> 2, c0 = (lane & 3) * 32;
  bf16x8 bfr[8][4];  // B fragments resident in registers (128 VGPRs)
#pragma unroll
  for (int nt = 0; nt < 8; ++nt)
#pragma unroll
    for (int t = 0; t < 4; ++t)
      bfr[nt][t] = *(const bf16x8*)&Wbt[(nt * 16 + c15) * 136 + t * 32 + q * 8];
  const int blk = blockIdx.x;
  const int b = blk >> 5;
  const size_t bbase = (size_t)b * 2048;
  const int p0 = (blk & 31) * 64 + wave * 16;
  for (int it = 0; it < 16; ++it) {
    const int pl = p0 + it;
    const size_t node = bbase + pl;
    const float* pp = pos + node * 3;
    const float xp = pp[0], yp = pp[1], zp = pp[2];
    {
      int c = lane * 2;
      float v0 = b1aL[c]     - (xp * Br0[c]     + yp * Br1[c]     + zp * Br2[c]);
      float v1 = b1aL[c + 1] - (xp * Br0[c + 1] + yp * Br1[c + 1] + zp * Br2[c + 1]);
      *(float2*)&base2[wave][c] = make_float2(v0, v1);
    }
    __syncthreads();
    const int j = nbr[node * 16 + kk];
    const float* pj = pos + (bbase + j) * 3;
    const float xj = pj[0], yj = pj[1], zj = pj[2];
#pragma unroll
    for (int ii = 0; ii < 4; ++ii) {
      int c = c0 + 8 * ii;
      bf16x8 v;
#pragma unroll
      for (int h = 0; h < 2; ++h) {
        int cc = c + 4 * h;
        float4 bb = *(const float4*)&base2[wave][cc];
        float4 s0 = *(const float4*)&S0[cc];
        float4 s1 = *(const float4*)&S1[cc];
        float4 s2 = *(const float4*)&S2[cc];
        v[4 * h + 0] = (__bf16)fmaxf(bb.x + xj * s0.x + yj * s1.x + zj * s2.x, 0.f);
        v[4 * h + 1] = (__bf16)fmaxf(bb.y + xj * s0.y + yj * s1.y + zj * s2.y, 0.f);
        v[4 * h + 2] = (__bf16)fmaxf(bb.z + xj * s0.z + yj * s1.z + zj * s2.z, 0.f);
        v[4 * h + 3] = (__bf16)fmaxf(bb.w + xj * s0.w + yj * s1.w + zj * s2.w, 0.f);
      }
      *(bf16x8*)&mt[wave][kk * 136 + c] = v;
    }
    __syncthreads();
    bf16x8 af[4];
#pragma unroll
    for (int t = 0; t < 4; ++t)
      af[t] = *(const bf16x8*)&mt[wave][c15 * 136 + t * 32 + q * 8];
    f32x4 acc[8] = {};
#pragma unroll
    for (int nt = 0; nt < 8; ++nt)
#pragma unroll
      for (int t = 0; t < 4; ++t)
        acc[nt] = __builtin_amdgcn_mfma_f32_16x16x32_bf16(af[t], bfr[nt][t], acc[nt], 0, 0, 0);
#pragma unroll
    for (int nt = 0; nt < 8; ++nt) {
      float m4 = fmaxf(fmaxf(acc[nt][0], acc[nt][1]), fmaxf(acc[nt][2], acc[nt][3]));
      m4 = fmaxf(m4, __shfl_xor(m4, 16));
      m4 = fmaxf(m4, __shfl_xor(m4, 32));
      if ((nt >> 1) == q) {
        float h = fmaxf(m4 + b1bL[nt * 16 + c15], 0.f);
        h1e[node * 160 + nt * 16 + c15] = (__bf16)h;
      }
    }
    if (lane < 32) {  // append pos (bf16) + zero pad: cols 128..159
      __bf16 v = (__bf16)0.f;
      if (lane == 0) v = (__bf16)xp;
      else if (lane == 1) v = (__bf16)yp;
      else if (lane == 2) v = (__bf16)zp;
      h1e[node * 160 + 128 + lane] = v;
    }
  }
}

// ---------------------------------------------------------------- K3: u2' = [h1|pos|0] @ W2a + b2a
__global__ __launch_bounds__(256, 2) void mid_gemm_kernel(
    const __bf16* __restrict__ h1e, const float* __restrict__ W2a,
    const float* __restrict__ b2a, float* __restrict__ u2p) {
  __shared__ LDSA __bf16 Wt[128 * 168];  // W2a^T [n][k], k padded 131->160(+8)
  __shared__ LDSA float b2aL[128];
  const int tid = threadIdx.x;
  for (int idx = tid; idx < 128 * 168; idx += 256) Wt[idx] = (__bf16)0.f;
  if (tid < 128) b2aL[tid] = b2a[tid];
  __syncthreads();
  for (int idx = tid; idx < 131 * 128; idx += 256) {
    int k = idx >> 7, n = idx & 127;
    Wt[n * 168 + k] = (__bf16)W2a[idx];
  }
  __syncthreads();
  const int wave = tid >> 6, lane = tid & 63;
  const int q = lane >> 4, c15 = lane & 15;
  const int row0 = (blockIdx.x * 4 + wave) * 16;
  bf16x8 af[5];
#pragma unroll
  for (int t = 0; t < 5; ++t)
    af[t] = *(const bf16x8*)(h1e + (size_t)(row0 + c15) * 160 + t * 32 + q * 8);
  f32x4 acc[8] = {};
#pragma unroll
  for (int nt = 0; nt < 8; ++nt)
#pragma unroll
    for (int t = 0; t < 5; ++t) {
      bf16x8 bf = *(const bf16x8*)&Wt[(nt * 16 + c15) * 168 + t * 32 + q * 8];
      acc[nt] = __builtin_amdgcn_mfma_f32_16x16x32_bf16(af[t], bf, acc[nt], 0, 0, 0);
    }
#pragma unroll
  for (int nt = 0; nt < 8; ++nt) {
    float bias = b2aL[nt * 16 + c15];
#pragma unroll
    for (int r = 0; r < 4; ++r)
      u2p[(size_t)(row0 + q * 4 + r) * 128 + nt * 16 + c15] = acc[nt][r] + bias;
  }
}

// ---------------------------------------------------------------- K4: layer 2 + fused max pool
__global__ __launch_bounds__(256, 2) void layer2_kernel(
    const float* __restrict__ pos, const int* __restrict__ nbr,
    const float* __restrict__ u2p, const float* __restrict__ W2a,
    const float* __restrict__ W2b, const float* __restrict__ b2b,
    int* __restrict__ gG) {
  __shared__ LDSA __bf16 Wbt[128 * 136];
  __shared__ LDSA __bf16 mt[4][16 * 136];
  __shared__ LDSA float R0[128], R1[128], R2[128];  // W2a rows 128..130
  __shared__ LDSA float b2bL[128];
  __shared__ LDSA float projp[4][128];
  __shared__ int gpart[128];
  const int tid = threadIdx.x;
  for (int idx = tid; idx < 16384; idx += 256) {
    int k = idx >> 7, n = idx & 127;
    Wbt[n * 136 + k] = (__bf16)W2b[idx];
  }
  if (tid < 128) {
    int c = tid;
    R0[c] = W2a[128 * 128 + c];
    R1[c] = W2a[129 * 128 + c];
    R2[c] = W2a[130 * 128 + c];
    b2bL[c] = b2b[c];
    gpart[c] = 0;
  }
  __syncthreads();
  const int wave = tid >> 6, lane = tid & 63;
  const int q = lane >> 4, c15 = lane & 15;
  const int kk = lane >> 2, c0 = (lane & 3) * 32;
  bf16x8 bfr[8][4];
#pragma unroll
  for (int nt = 0; nt < 8; ++nt)
#pragma unroll
    for (int t = 0; t < 4; ++t)
      bfr[nt][t] = *(const bf16x8*)&Wbt[(nt * 16 + c15) * 136 + t * 32 + q * 8];
  const int blk = blockIdx.x;
  const int b = blk >> 5;
  const size_t bbase = (size_t)b * 2048;
  const int p0 = (blk & 31) * 64 + wave * 16;
  for (int it = 0; it < 16; ++it) {
    const int pl = p0 + it;
    const size_t node = bbase + pl;
    const float* pp = pos + node * 3;
    const float xp = pp[0], yp = pp[1], zp = pp[2];
    {
      int c = lane * 2;
      float v0 = xp * R0[c]     + yp * R1[c]     + zp * R2[c];
      float v1 = xp * R0[c + 1] + yp * R1[c + 1] + zp * R2[c + 1];
      *(float2*)&projp[wave][c] = make_float2(v0, v1);
    }
    __syncthreads();
    const int j = nbr[node * 16 + kk];
    const float* ur = u2p + (bbase + j) * 128;
#pragma unroll
    for (int ii = 0; ii < 4; ++ii) {
      int c = c0 + 8 * ii;
      bf16x8 v;
#pragma unroll
      for (int h = 0; h < 2; ++h) {
        int cc = c + 4 * h;
        float4 uu = *(const float4*)&ur[cc];
        float4 pj = *(const float4*)&projp[wave][cc];
        v[4 * h + 0] = (__bf16)fmaxf(uu.x - pj.x, 0.f);
        v[4 * h + 1] = (__bf16)fmaxf(uu.y - pj.y, 0.f);
        v[4 * h + 2] = (__bf16)fmaxf(uu.z - pj.z, 0.f);
        v[4 * h + 3] = (__bf16)fmaxf(uu.w - pj.w, 0.f);
      }
      *(bf16x8*)&mt[wave][kk * 136 + c] = v;
    }
    __syncthreads();
    bf16x8 af[4];
#pragma unroll
    for (int t = 0; t < 4; ++t)
      af[t] = *(const bf16x8*)&mt[wave][c15 * 136 + t * 32 + q * 8];
    f32x4 acc[8] = {};
#pragma unroll
    for (int nt = 0; nt < 8; ++nt)
#pragma unroll
      for (int t = 0; t < 4; ++t)
        acc[nt] = __builtin_amdgcn_mfma_f32_16x16x32_bf16(af[t], bfr[nt][t], acc[nt], 0, 0, 0);
#pragma unroll
    for (int nt = 0; nt < 8; ++nt) {
      float m4 = fmaxf(fmaxf(acc[nt][0], acc[nt][1]), fmaxf(acc[nt][2], acc[nt][3]));
      m4 = fmaxf(m4, __shfl_xor(m4, 16));
      m4 = fmaxf(m4, __shfl_xor(m4, 32));
      if ((nt >> 1) == q) {
        float h = fmaxf(m4 + b2bL[nt * 16 + c15], 0.f);
        atomicMax(&gpart[nt * 16 + c15], __float_as_int(h));  // h>=0: int-max == float-max
      }
    }
  }
  __syncthreads();
  if (tid < 128) atomicMax(&gG[b * 128 + tid], gpart[tid]);
}

// ---------------------------------------------------------------- K5: classifier
__global__ __launch_bounds__(64) void cls_kernel(const int* __restrict__ gG,
                                                 const float* __restrict__ Wc,
                                                 const float* __restrict__ bc,
                                                 float* __restrict__ out) {
  const int b = blockIdx.x, lane = threadIdx.x;
  float g1 = __int_as_float(gG[b * 128 + lane]);
  float g2 = __int_as_float(gG[b * 128 + 64 + lane]);
  float accn[10];
#pragma unroll
  for (int n = 0; n < 10; ++n)
    accn[n] = g1 * Wc[lane * 10 + n] + g2 * Wc[(64 + lane) * 10 + n];
#pragma unroll
  for (int n = 0; n < 10; ++n) {
#pragma unroll
    for (int off = 32; off >= 1; off >>= 1) accn[n] += __shfl_xor(accn[n], off);
  }
  if (lane == 0) {
#pragma unroll
    for (int n = 0; n < 10; ++n) out[b * 10 + n] = accn[n] + bc[n];
  }
}

// ---------------------------------------------------------------- launcher
extern "C" void kernel_launch(void* const* d_in, const int* in_sizes, int n_in,
                              void* d_out, int out_size, void* d_ws, size_t ws_size,
                              hipStream_t stream) {
  const float* pos = (const float*)d_in[0];
  // d_in[1] = batch (unused: graphs are equal-size, sorted)
  const float* W1a = (const float*)d_in[2];
  const float* b1a = (const float*)d_in[3];
  const float* W1b = (const float*)d_in[4];
  const float* b1b = (const float*)d_in[5];
  const float* W2a = (const float*)d_in[6];
  const float* b2a = (const float*)d_in[7];
  const float* W2b = (const float*)d_in[8];
  const float* b2b = (const float*)d_in[9];
  const float* Wc  = (const float*)d_in[10];
  const float* bc  = (const float*)d_in[11];

  char* ws = (char*)d_ws;
  int*    nbr = (int*)ws;                          //  4 MB : [65536][16]
  __bf16* h1e = (__bf16*)(ws + 4194304);           // 20 MB : [65536][160]
  float*  u2p = (float*)(ws + 25165824);           // 32 MB : [65536][128]
  int*    gG  = (int*)(ws + 58720256);             // 16 KB : [32][128]
  float*  out = (float*)d_out;

  hipMemsetAsync(gG, 0, 32 * 128 * sizeof(int), stream);  // relu>=0, bits(0)==0.0f
  knn_kernel<<<1024, 256, 0, stream>>>(pos, nbr);
  layer1_kernel<<<1024, 256, 0, stream>>>(pos, nbr, W1a, b1a, W1b, b1b, h1e);
  mid_gemm_kernel<<<1024, 256, 0, stream>>>(h1e, W2a, b2a, u2p);
  layer2_kernel<<<1024, 256, 0, stream>>>(pos, nbr, u2p, W2a, W2b, b2b, gG);
  cls_kernel<<<32, 64, 0, stream>>>(gG, Wc, bc, out);
}

// Round 2
// 527.967 us; speedup vs baseline: 1.6689x; 1.6689x over previous
//
#include <hip/hip_runtime.h>

// PointNet on MI355X.
// B=32, P=2048, K=16, NHID=128, NCLS=10.
// Pipeline:
//   K1 knn      : brute-force d2; per-lane streaming sorted top-3 buffer (u32 monotone d2-key + idx),
//                 16 merge rounds with a single packed-u64 (key,idx) wave min-reduce per round
//                 (exact top_k tie-break = (d2, then smaller index)); rare exec-masked refill when a
//                 lane contributes >3 of the top-16 (exact: pops occur in ascending global key order).
//   K2 layer1   : msg = relu(pos_j*(A+B) + (b1a - pos_p*B)); v = msg @ W1b (MFMA); h1 = relu(max_k v + b1b)
//   K3 midgemm  : u2' = [h1|pos|0] @ W2a(all 131 rows) + b2a
//   K4 layer2   : msg = relu(u2'[j] - pos_p*R); v = msg @ W2b (MFMA); fused global max pool
//   K5 cls      : out = g @ Wc + bc
// MFMA layouts per verified m89/m97 mappings.

typedef __bf16 bf16x8 __attribute__((ext_vector_type(8)));
typedef float  f32x4  __attribute__((ext_vector_type(4)));

#define LDSA __attribute__((aligned(16)))

// ---------------------------------------------------------------- K1: KNN
__global__ __launch_bounds__(512, 4) void knn_kernel(const float* __restrict__ pos,
                                                     int* __restrict__ nbr) {
  __shared__ LDSA float4 P4[2048];  // {x,y,z,|p|^2} per node of this batch
  const unsigned EMPTY = 0xFFFFFFFFu;
  const int blk = blockIdx.x;
  const int b = blk >> 4;                 // 16 blocks per batch
  const int tid = threadIdx.x;
  const size_t bbase = (size_t)b * 2048;
  for (int idx = tid; idx < 2048; idx += 512) {
    const float* pp = pos + (bbase + idx) * 3;
    float x = pp[0], y = pp[1], z = pp[2];
    float sq = fmaf(z, z, fmaf(y, y, x * x));
    P4[idx] = make_float4(x, y, z, sq);
  }
  __syncthreads();
  const int wave = tid >> 6, lane = tid & 63;
  const int p0 = (blk & 15) * 128 + wave * 16;
  for (int it = 0; it < 16; ++it) {
    const int pl = p0 + it;
    const float4 P = P4[pl];
    // ---- phase 1: streaming per-lane sorted top-3 (keys ascending) ----
    unsigned m1 = EMPTY, m2 = EMPTY, m3 = EMPTY;
    unsigned s1 = 0, s2 = 0, s3 = 0;
#pragma unroll 4
    for (int i = 0; i < 32; ++i) {
      int c = lane + (i << 6);
      float4 Q = P4[c];
      float d2 = (P.w + Q.w) - 2.0f * fmaf(P.z, Q.z, fmaf(P.y, Q.y, P.x * Q.x));
      unsigned u = __float_as_uint(d2);
      u = ((int)u < 0) ? ~u : (u | 0x80000000u);  // monotone float->u32
      bool c3 = u < m3, c2 = u < m2, c1 = u < m1;
      m3 = c2 ? m2 : (c3 ? u : m3);  s3 = c2 ? s2 : (c3 ? (unsigned)c : s3);
      m2 = c1 ? m1 : (c2 ? u : m2);  s2 = c1 ? s1 : (c2 ? (unsigned)c : s2);
      m1 = c1 ? u : m1;              s1 = c1 ? (unsigned)c : s1;
    }
    // ---- phase 2: 16 merge rounds, one packed u64 min-reduce each ----
    unsigned long long lastk = 0;
    const long long outbase = ((long long)bbase + pl) * 16;
    for (int r = 0; r < 16; ++r) {
      unsigned long long k = ((unsigned long long)m1 << 32) | s1;
      unsigned long long kmin = k;
#pragma unroll
      for (int off = 1; off < 64; off <<= 1) {
        unsigned long long o = __shfl_xor(kmin, off);
        kmin = (o < kmin) ? o : kmin;
      }
      if (lane == r) nbr[outbase + r] = (int)(kmin & 0xFFFFFFFFull);
      bool iwin = (k == kmin);
      if (iwin) {  // pop head (predicated selects)
        lastk = k;
        m1 = m2; s1 = s2;
        m2 = m3; s2 = s3;
        m3 = EMPTY;
      }
      // rare exact refill: a lane exhausted its 3 buffered elements
      if (r < 15 && __any(m1 == EMPTY)) {
        if (m1 == EMPTY) {
          unsigned nm = EMPTY, ns = 0;
          for (int i = 0; i < 32; ++i) {
            int c = lane + (i << 6);
            float4 Q = P4[c];
            float d2 = (P.w + Q.w) - 2.0f * fmaf(P.z, Q.z, fmaf(P.y, Q.y, P.x * Q.x));
            unsigned u = __float_as_uint(d2);
            u = ((int)u < 0) ? ~u : (u | 0x80000000u);
            unsigned long long kc = ((unsigned long long)u << 32) | (unsigned)c;
            bool ok = (kc > lastk) & (u < nm);  // ascending c => first min kept (smallest idx)
            nm = ok ? u : nm;
            ns = ok ? (unsigned)c : ns;
          }
          m1 = nm; s1 = ns;  // m2,m3 stay EMPTY
        }
      }
    }
  }
}

// ---------------------------------------------------------------- K2: layer 1
__global__ __launch_bounds__(256, 2) void layer1_kernel(
    const float* __restrict__ pos, const int* __restrict__ nbr,
    const float* __restrict__ W1a, const float* __restrict__ b1a,
    const float* __restrict__ W1b, const float* __restrict__ b1b,
    __bf16* __restrict__ h1e) {
  __shared__ LDSA __bf16 Wbt[128 * 136];       // W1b^T [n][k], row pad to 136
  __shared__ LDSA __bf16 mt[4][16 * 136];      // per-wave message tile [k-neigh][c]
  __shared__ LDSA float S0[128], S1[128], S2[128];   // rows of (A+B)
  __shared__ LDSA float Br0[128], Br1[128], Br2[128];// rows of B (rel part of W1a)
  __shared__ LDSA float b1aL[128], b1bL[128];
  __shared__ LDSA float base2[4][128];
  const int tid = threadIdx.x;
  for (int idx = tid; idx < 16384; idx += 256) {
    int k = idx >> 7, n = idx & 127;
    Wbt[n * 136 + k] = (__bf16)W1b[idx];
  }
  if (tid < 128) {
    int c = tid;
    float a0 = W1a[c], a1 = W1a[128 + c], a2 = W1a[256 + c];
    float r0 = W1a[384 + c], r1 = W1a[512 + c], r2 = W1a[640 + c];
    S0[c] = a0 + r0; S1[c] = a1 + r1; S2[c] = a2 + r2;
    Br0[c] = r0; Br1[c] = r1; Br2[c] = r2;
    b1aL[c] = b1a[c]; b1bL[c] = b1b[c];
  }
  __syncthreads();
  const int wave = tid >> 6, lane = tid & 63;
  const int q = lane >> 4, c15 = lane & 15;
  const int kk = lane >> 2, c0 = (lane & 3) * 32;
  bf16x8 bfr[8][4];  // B fragments resident in registers (128 VGPRs)
#pragma unroll
  for (int nt = 0; nt < 8; ++nt)
#pragma unroll
    for (int t = 0; t < 4; ++t)
      bfr[nt][t] = *(const bf16x8*)&Wbt[(nt * 16 + c15) * 136 + t * 32 + q * 8];
  const int blk = blockIdx.x;
  const int b = blk >> 5;
  const size_t bbase = (size_t)b * 2048;
  const int p0 = (blk & 31) * 64 + wave * 16;
  for (int it = 0; it < 16; ++it) {
    const int pl = p0 + it;
    const size_t node = bbase + pl;
    const float* pp = pos + node * 3;
    const float xp = pp[0], yp = pp[1], zp = pp[2];
    {
      int c = lane * 2;
      float v0 = b1aL[c]     - (xp * Br0[c]     + yp * Br1[c]     + zp * Br2[c]);
      float v1 = b1aL[c + 1] - (xp * Br0[c + 1] + yp * Br1[c + 1] + zp * Br2[c + 1]);
      *(float2*)&base2[wave][c] = make_float2(v0, v1);
    }
    __syncthreads();
    const int j = nbr[node * 16 + kk];
    const float* pj = pos + (bbase + j) * 3;
    const float xj = pj[0], yj = pj[1], zj = pj[2];
#pragma unroll
    for (int ii = 0; ii < 4; ++ii) {
      int c = c0 + 8 * ii;
      bf16x8 v;
#pragma unroll
      for (int h = 0; h < 2; ++h) {
        int cc = c + 4 * h;
        float4 bb = *(const float4*)&base2[wave][cc];
        float4 s0 = *(const float4*)&S0[cc];
        float4 s1 = *(const float4*)&S1[cc];
        float4 s2 = *(const float4*)&S2[cc];
        v[4 * h + 0] = (__bf16)fmaxf(bb.x + xj * s0.x + yj * s1.x + zj * s2.x, 0.f);
        v[4 * h + 1] = (__bf16)fmaxf(bb.y + xj * s0.y + yj * s1.y + zj * s2.y, 0.f);
        v[4 * h + 2] = (__bf16)fmaxf(bb.z + xj * s0.z + yj * s1.z + zj * s2.z, 0.f);
        v[4 * h + 3] = (__bf16)fmaxf(bb.w + xj * s0.w + yj * s1.w + zj * s2.w, 0.f);
      }
      *(bf16x8*)&mt[wave][kk * 136 + c] = v;
    }
    __syncthreads();
    bf16x8 af[4];
#pragma unroll
    for (int t = 0; t < 4; ++t)
      af[t] = *(const bf16x8*)&mt[wave][c15 * 136 + t * 32 + q * 8];
    f32x4 acc[8] = {};
#pragma unroll
    for (int nt = 0; nt < 8; ++nt)
#pragma unroll
      for (int t = 0; t < 4; ++t)
        acc[nt] = __builtin_amdgcn_mfma_f32_16x16x32_bf16(af[t], bfr[nt][t], acc[nt], 0, 0, 0);
#pragma unroll
    for (int nt = 0; nt < 8; ++nt) {
      float m4 = fmaxf(fmaxf(acc[nt][0], acc[nt][1]), fmaxf(acc[nt][2], acc[nt][3]));
      m4 = fmaxf(m4, __shfl_xor(m4, 16));
      m4 = fmaxf(m4, __shfl_xor(m4, 32));
      if ((nt >> 1) == q) {
        float h = fmaxf(m4 + b1bL[nt * 16 + c15], 0.f);
        h1e[node * 160 + nt * 16 + c15] = (__bf16)h;
      }
    }
    if (lane < 32) {  // append pos (bf16) + zero pad: cols 128..159
      __bf16 v = (__bf16)0.f;
      if (lane == 0) v = (__bf16)xp;
      else if (lane == 1) v = (__bf16)yp;
      else if (lane == 2) v = (__bf16)zp;
      h1e[node * 160 + 128 + lane] = v;
    }
  }
}

// ---------------------------------------------------------------- K3: u2' = [h1|pos|0] @ W2a + b2a
__global__ __launch_bounds__(256, 2) void mid_gemm_kernel(
    const __bf16* __restrict__ h1e, const float* __restrict__ W2a,
    const float* __restrict__ b2a, float* __restrict__ u2p) {
  __shared__ LDSA __bf16 Wt[128 * 168];  // W2a^T [n][k], k padded 131->160(+8)
  __shared__ LDSA float b2aL[128];
  const int tid = threadIdx.x;
  for (int idx = tid; idx < 128 * 168; idx += 256) Wt[idx] = (__bf16)0.f;
  if (tid < 128) b2aL[tid] = b2a[tid];
  __syncthreads();
  for (int idx = tid; idx < 131 * 128; idx += 256) {
    int k = idx >> 7, n = idx & 127;
    Wt[n * 168 + k] = (__bf16)W2a[idx];
  }
  __syncthreads();
  const int wave = tid >> 6, lane = tid & 63;
  const int q = lane >> 4, c15 = lane & 15;
  const int row0 = (blockIdx.x * 4 + wave) * 16;
  bf16x8 af[5];
#pragma unroll
  for (int t = 0; t < 5; ++t)
    af[t] = *(const bf16x8*)(h1e + (size_t)(row0 + c15) * 160 + t * 32 + q * 8);
  f32x4 acc[8] = {};
#pragma unroll
  for (int nt = 0; nt < 8; ++nt)
#pragma unroll
    for (int t = 0; t < 5; ++t) {
      bf16x8 bf = *(const bf16x8*)&Wt[(nt * 16 + c15) * 168 + t * 32 + q * 8];
      acc[nt] = __builtin_amdgcn_mfma_f32_16x16x32_bf16(af[t], bf, acc[nt], 0, 0, 0);
    }
#pragma unroll
  for (int nt = 0; nt < 8; ++nt) {
    float bias = b2aL[nt * 16 + c15];
#pragma unroll
    for (int r = 0; r < 4; ++r)
      u2p[(size_t)(row0 + q * 4 + r) * 128 + nt * 16 + c15] = acc[nt][r] + bias;
  }
}

// ---------------------------------------------------------------- K4: layer 2 + fused max pool
__global__ __launch_bounds__(256, 2) void layer2_kernel(
    const float* __restrict__ pos, const int* __restrict__ nbr,
    const float* __restrict__ u2p, const float* __restrict__ W2a,
    const float* __restrict__ W2b, const float* __restrict__ b2b,
    int* __restrict__ gG) {
  __shared__ LDSA __bf16 Wbt[128 * 136];
  __shared__ LDSA __bf16 mt[4][16 * 136];
  __shared__ LDSA float R0[128], R1[128], R2[128];  // W2a rows 128..130
  __shared__ LDSA float b2bL[128];
  __shared__ LDSA float projp[4][128];
  __shared__ int gpart[128];
  const int tid = threadIdx.x;
  for (int idx = tid; idx < 16384; idx += 256) {
    int k = idx >> 7, n = idx & 127;
    Wbt[n * 136 + k] = (__bf16)W2b[idx];
  }
  if (tid < 128) {
    int c = tid;
    R0[c] = W2a[128 * 128 + c];
    R1[c] = W2a[129 * 128 + c];
    R2[c] = W2a[130 * 128 + c];
    b2bL[c] = b2b[c];
    gpart[c] = 0;
  }
  __syncthreads();
  const int wave = tid >> 6, lane = tid & 63;
  const int q = lane >> 4, c15 = lane & 15;
  const int kk = lane >> 2, c0 = (lane & 3) * 32;
  bf16x8 bfr[8][4];
#pragma unroll
  for (int nt = 0; nt < 8; ++nt)
#pragma unroll
    for (int t = 0; t < 4; ++t)
      bfr[nt][t] = *(const bf16x8*)&Wbt[(nt * 16 + c15) * 136 + t * 32 + q * 8];
  const int blk = blockIdx.x;
  const int b = blk >> 5;
  const size_t bbase = (size_t)b * 2048;
  const int p0 = (blk & 31) * 64 + wave * 16;
  for (int it = 0; it < 16; ++it) {
    const int pl = p0 + it;
    const size_t node = bbase + pl;
    const float* pp = pos + node * 3;
    const float xp = pp[0], yp = pp[1], zp = pp[2];
    {
      int c = lane * 2;
      float v0 = xp * R0[c]     + yp * R1[c]     + zp * R2[c];
      float v1 = xp * R0[c + 1] + yp * R1[c + 1] + zp * R2[c + 1];
      *(float2*)&projp[wave][c] = make_float2(v0, v1);
    }
    __syncthreads();
    const int j = nbr[node * 16 + kk];
    const float* ur = u2p + (bbase + j) * 128;
#pragma unroll
    for (int ii = 0; ii < 4; ++ii) {
      int c = c0 + 8 * ii;
      bf16x8 v;
#pragma unroll
      for (int h = 0; h < 2; ++h) {
        int cc = c + 4 * h;
        float4 uu = *(const float4*)&ur[cc];
        float4 pj = *(const float4*)&projp[wave][cc];
        v[4 * h + 0] = (__bf16)fmaxf(uu.x - pj.x, 0.f);
        v[4 * h + 1] = (__bf16)fmaxf(uu.y - pj.y, 0.f);
        v[4 * h + 2] = (__bf16)fmaxf(uu.z - pj.z, 0.f);
        v[4 * h + 3] = (__bf16)fmaxf(uu.w - pj.w, 0.f);
      }
      *(bf16x8*)&mt[wave][kk * 136 + c] = v;
    }
    __syncthreads();
    bf16x8 af[4];
#pragma unroll
    for (int t = 0; t < 4; ++t)
      af[t] = *(const bf16x8*)&mt[wave][c15 * 136 + t * 32 + q * 8];
    f32x4 acc[8] = {};
#pragma unroll
    for (int nt = 0; nt < 8; ++nt)
#pragma unroll
      for (int t = 0; t < 4; ++t)
        acc[nt] = __builtin_amdgcn_mfma_f32_16x16x32_bf16(af[t], bfr[nt][t], acc[nt], 0, 0, 0);
#pragma unroll
    for (int nt = 0; nt < 8; ++nt) {
      float m4 = fmaxf(fmaxf(acc[nt][0], acc[nt][1]), fmaxf(acc[nt][2], acc[nt][3]));
      m4 = fmaxf(m4, __shfl_xor(m4, 16));
      m4 = fmaxf(m4, __shfl_xor(m4, 32));
      if ((nt >> 1) == q) {
        float h = fmaxf(m4 + b2bL[nt * 16 + c15], 0.f);
        atomicMax(&gpart[nt * 16 + c15], __float_as_int(h));  // h>=0: int-max == float-max
      }
    }
  }
  __syncthreads();
  if (tid < 128) atomicMax(&gG[b * 128 + tid], gpart[tid]);
}

// ---------------------------------------------------------------- K5: classifier
__global__ __launch_bounds__(64) void cls_kernel(const int* __restrict__ gG,
                                                 const float* __restrict__ Wc,
                                                 const float* __restrict__ bc,
                                                 float* __restrict__ out) {
  const int b = blockIdx.x, lane = threadIdx.x;
  float g1 = __int_as_float(gG[b * 128 + lane]);
  float g2 = __int_as_float(gG[b * 128 + 64 + lane]);
  float accn[10];
#pragma unroll
  for (int n = 0; n < 10; ++n)
    accn[n] = g1 * Wc[lane * 10 + n] + g2 * Wc[(64 + lane) * 10 + n];
#pragma unroll
  for (int n = 0; n < 10; ++n) {
#pragma unroll
    for (int off = 32; off >= 1; off >>= 1) accn[n] += __shfl_xor(accn[n], off);
  }
  if (lane == 0) {
#pragma unroll
    for (int n = 0; n < 10; ++n) out[b * 10 + n] = accn[n] + bc[n];
  }
}

// ---------------------------------------------------------------- launcher
extern "C" void kernel_launch(void* const* d_in, const int* in_sizes, int n_in,
                              void* d_out, int out_size, void* d_ws, size_t ws_size,
                              hipStream_t stream) {
  const float* pos = (const float*)d_in[0];
  // d_in[1] = batch (unused: graphs are equal-size, sorted)
  const float* W1a = (const float*)d_in[2];
  const float* b1a = (const float*)d_in[3];
  const float* W1b = (const float*)d_in[4];
  const float* b1b = (const float*)d_in[5];
  const float* W2a = (const float*)d_in[6];
  const float* b2a = (const float*)d_in[7];
  const float* W2b = (const float*)d_in[8];
  const float* b2b = (const float*)d_in[9];
  const float* Wc  = (const float*)d_in[10];
  const float* bc  = (const float*)d_in[11];

  char* ws = (char*)d_ws;
  int*    nbr = (int*)ws;                          //  4 MB : [65536][16]
  __bf16* h1e = (__bf16*)(ws + 4194304);           // 20 MB : [65536][160]
  float*  u2p = (float*)(ws + 25165824);           // 32 MB : [65536][128]
  int*    gG  = (int*)(ws + 58720256);             // 16 KB : [32][128]
  float*  out = (float*)d_out;

  hipMemsetAsync(gG, 0, 32 * 128 * sizeof(int), stream);  // relu>=0, bits(0)==0.0f
  knn_kernel<<<512, 512, 0, stream>>>(pos, nbr);
  layer1_kernel<<<1024, 256, 0, stream>>>(pos, nbr, W1a, b1a, W1b, b1b, h1e);
  mid_gemm_kernel<<<1024, 256, 0, stream>>>(h1e, W2a, b2a, u2p);
  layer2_kernel<<<1024, 256, 0, stream>>>(pos, nbr, u2p, W2a, W2b, b2b, gG);
  cls_kernel<<<32, 64, 0, stream>>>(gG, Wc, bc, out);
}

// Round 3
// 438.818 us; speedup vs baseline: 2.0080x; 1.2032x over previous
//
#include <hip/hip_runtime.h>

// PointNet on MI355X. B=32, P=2048, K=16, NHID=128, NCLS=10.
//   K1 knn      : brute-force d2; per-lane streaming sorted top-3 + 16 packed-u64 min-reduce rounds
//                 (exact top_k tie-break), rare exec-masked refill. Grid 1024 for 32 waves/CU.
//   K2 layer1   : msg = relu(pos_j*(A+B) + (b1a - pos_p*B)); v = msg @ W1b (MFMA); h1 = relu(max_k v + b1b)
//                 No in-loop barriers: mt/base are wave-private, ordered by s_waitcnt lgkmcnt(0).
//                 S=(A+B) hoisted into 48 VGPRs (2 neighbors x 16 channels per lane).
//   K3 midgemm  : u2' = [h1|pos|0] @ W2a(all 131 rows) + b2a (float4 staging)
//   K4 layer2   : msg = relu(u2'[j] - pos_p*R); v = msg @ W2b (MFMA); fused global max pool
//   K5 cls      : out = g @ Wc + bc
// MFMA layouts per verified m89/m97 mappings.

typedef __bf16 bf16x8 __attribute__((ext_vector_type(8)));
typedef float  f32x4  __attribute__((ext_vector_type(4)));

#define LDSA __attribute__((aligned(16)))
// wave-private LDS write->read ordering (DS pipe is in-order per wave; this drains outstanding ops)
#define WAVE_LDS_SYNC() __asm__ volatile("s_waitcnt lgkmcnt(0)" ::: "memory")

// ---------------------------------------------------------------- K1: KNN
__global__ __launch_bounds__(512, 4) void knn_kernel(const float* __restrict__ pos,
                                                     int* __restrict__ nbr) {
  __shared__ LDSA float4 P4[2048];  // {x,y,z,|p|^2}
  const unsigned EMPTY = 0xFFFFFFFFu;
  const int blk = blockIdx.x;
  const int b = blk >> 5;                 // 32 blocks per batch
  const int tid = threadIdx.x;
  const size_t bbase = (size_t)b * 2048;
  for (int idx = tid; idx < 2048; idx += 512) {
    const float* pp = pos + (bbase + idx) * 3;
    float x = pp[0], y = pp[1], z = pp[2];
    float sq = fmaf(z, z, fmaf(y, y, x * x));
    P4[idx] = make_float4(x, y, z, sq);
  }
  __syncthreads();
  const int wave = tid >> 6, lane = tid & 63;
  const int p0 = (blk & 31) * 64 + wave * 8;   // 8 points per wave
  for (int it = 0; it < 8; ++it) {
    const int pl = p0 + it;
    const float4 P = P4[pl];
    // ---- phase 1: streaming per-lane sorted top-3 ----
    unsigned m1 = EMPTY, m2 = EMPTY, m3 = EMPTY;
    unsigned s1 = 0, s2 = 0, s3 = 0;
#pragma unroll 4
    for (int i = 0; i < 32; ++i) {
      int c = lane + (i << 6);
      float4 Q = P4[c];
      float d2 = (P.w + Q.w) - 2.0f * fmaf(P.z, Q.z, fmaf(P.y, Q.y, P.x * Q.x));
      unsigned u = __float_as_uint(d2);
      u = ((int)u < 0) ? ~u : (u | 0x80000000u);  // monotone float->u32
      bool c3 = u < m3, c2 = u < m2, c1 = u < m1;
      m3 = c2 ? m2 : (c3 ? u : m3);  s3 = c2 ? s2 : (c3 ? (unsigned)c : s3);
      m2 = c1 ? m1 : (c2 ? u : m2);  s2 = c1 ? s1 : (c2 ? (unsigned)c : s2);
      m1 = c1 ? u : m1;              s1 = c1 ? (unsigned)c : s1;
    }
    // ---- phase 2: 16 merge rounds, one packed u64 min-reduce each ----
    unsigned long long lastk = 0;
    const long long outbase = ((long long)bbase + pl) * 16;
    for (int r = 0; r < 16; ++r) {
      unsigned long long k = ((unsigned long long)m1 << 32) | s1;
      unsigned long long kmin = k;
#pragma unroll
      for (int off = 1; off < 64; off <<= 1) {
        unsigned long long o = __shfl_xor(kmin, off);
        kmin = (o < kmin) ? o : kmin;
      }
      if (lane == r) nbr[outbase + r] = (int)(kmin & 0xFFFFFFFFull);
      if (k == kmin) {  // pop head
        lastk = k;
        m1 = m2; s1 = s2;
        m2 = m3; s2 = s3;
        m3 = EMPTY;
      }
      if (r < 15 && __any(m1 == EMPTY)) {  // rare exact refill
        if (m1 == EMPTY) {
          unsigned nm = EMPTY, ns = 0;
          for (int i = 0; i < 32; ++i) {
            int c = lane + (i << 6);
            float4 Q = P4[c];
            float d2 = (P.w + Q.w) - 2.0f * fmaf(P.z, Q.z, fmaf(P.y, Q.y, P.x * Q.x));
            unsigned u = __float_as_uint(d2);
            u = ((int)u < 0) ? ~u : (u | 0x80000000u);
            unsigned long long kc = ((unsigned long long)u << 32) | (unsigned)c;
            bool ok = (kc > lastk) & (u < nm);
            nm = ok ? u : nm;
            ns = ok ? (unsigned)c : ns;
          }
          m1 = nm; s1 = ns;
        }
      }
    }
  }
}

// ---------------------------------------------------------------- K2: layer 1
__global__ __launch_bounds__(256, 2) void layer1_kernel(
    const float* __restrict__ pos, const int* __restrict__ nbr,
    const float* __restrict__ W1a, const float* __restrict__ b1a,
    const float* __restrict__ W1b, const float* __restrict__ b1b,
    __bf16* __restrict__ h1e) {
  // LDS: Wbt (34816 B) aliased with { mt 4x2176 bf16 (17408 B) ; base 4x128 f32 (2048 B) }
  __shared__ LDSA char smem[34816];
  __bf16* Wbt = (__bf16*)smem;
  const int tid = threadIdx.x;
  for (int idx = tid; idx < 16384; idx += 256) {
    int k = idx >> 7, n = idx & 127;
    Wbt[n * 136 + k] = (__bf16)W1b[idx];
  }
  __syncthreads();
  const int wave = tid >> 6, lane = tid & 63;
  const int q = lane >> 4, c15 = lane & 15;
  bf16x8 bfr[8][4];  // W1b^T fragments resident (128 VGPRs)
#pragma unroll
  for (int nt = 0; nt < 8; ++nt)
#pragma unroll
    for (int t = 0; t < 4; ++t)
      bfr[nt][t] = *(const bf16x8*)&Wbt[(nt * 16 + c15) * 136 + t * 32 + q * 8];
  __syncthreads();  // Wbt dead: its space now holds mt/base
  __bf16* mt = (__bf16*)smem + wave * 2176;          // [16 rows][136]
  float* base = (float*)(smem + 17408) + wave * 128;
  // per-lane hoisted constants
  const int cb = lane & 7, k0 = lane >> 3, C0 = cb * 16;
  float4 s0h[4], s1h[4], s2h[4];  // (A+B) rows for this lane's 16 channels
#pragma unroll
  for (int i = 0; i < 4; ++i) {
    float4 a0 = *(const float4*)&W1a[      C0 + 4 * i], r0 = *(const float4*)&W1a[384 + C0 + 4 * i];
    float4 a1 = *(const float4*)&W1a[128 + C0 + 4 * i], r1 = *(const float4*)&W1a[512 + C0 + 4 * i];
    float4 a2 = *(const float4*)&W1a[256 + C0 + 4 * i], r2 = *(const float4*)&W1a[640 + C0 + 4 * i];
    s0h[i] = make_float4(a0.x + r0.x, a0.y + r0.y, a0.z + r0.z, a0.w + r0.w);
    s1h[i] = make_float4(a1.x + r1.x, a1.y + r1.y, a1.z + r1.z, a1.w + r1.w);
    s2h[i] = make_float4(a2.x + r2.x, a2.y + r2.y, a2.z + r2.z, a2.w + r2.w);
  }
  const int c2 = lane * 2;
  const float br0a = W1a[384 + c2], br0b = W1a[384 + c2 + 1];
  const float br1a = W1a[512 + c2], br1b = W1a[512 + c2 + 1];
  const float br2a = W1a[640 + c2], br2b = W1a[640 + c2 + 1];
  const float ba0 = b1a[c2], ba1 = b1a[c2 + 1];
  const float bbi0 = b1b[q * 32 + c15], bbi1 = b1b[q * 32 + 16 + c15];
  const int blk = blockIdx.x, b = blk >> 5;
  const size_t bbase = (size_t)b * 2048;
  const int p0 = (blk & 31) * 64 + wave * 16;
  for (int it = 0; it < 16; ++it) {
    const size_t node = bbase + p0 + it;
    const float* pp = pos + node * 3;
    const float xp = pp[0], yp = pp[1], zp = pp[2];
    const int j0 = nbr[node * 16 + k0];
    const int j1 = nbr[node * 16 + k0 + 8];
    const float* pj0 = pos + (bbase + j0) * 3;
    const float* pj1 = pos + (bbase + j1) * 3;
    const float xa = pj0[0], ya = pj0[1], za = pj0[2];
    const float xb = pj1[0], yb = pj1[1], zb = pj1[2];
    float v0 = ba0 - fmaf(xp, br0a, fmaf(yp, br1a, zp * br2a));
    float v1 = ba1 - fmaf(xp, br0b, fmaf(yp, br1b, zp * br2b));
    *(float2*)&base[c2] = make_float2(v0, v1);
    WAVE_LDS_SYNC();
    float4 bb[4];
#pragma unroll
    for (int i = 0; i < 4; ++i) bb[i] = *(const float4*)&base[C0 + 4 * i];
#pragma unroll
    for (int r = 0; r < 2; ++r) {
      const float xj = r ? xb : xa, yj = r ? yb : ya, zj = r ? zb : za;
      bf16x8 o0, o1;
#pragma unroll
      for (int i = 0; i < 4; ++i) {
        float mx = fmaf(xj, s0h[i].x, fmaf(yj, s1h[i].x, fmaf(zj, s2h[i].x, bb[i].x)));
        float my = fmaf(xj, s0h[i].y, fmaf(yj, s1h[i].y, fmaf(zj, s2h[i].y, bb[i].y)));
        float mz = fmaf(xj, s0h[i].z, fmaf(yj, s1h[i].z, fmaf(zj, s2h[i].z, bb[i].z)));
        float mw = fmaf(xj, s0h[i].w, fmaf(yj, s1h[i].w, fmaf(zj, s2h[i].w, bb[i].w)));
        __bf16 e0 = (__bf16)fmaxf(mx, 0.f), e1 = (__bf16)fmaxf(my, 0.f);
        __bf16 e2 = (__bf16)fmaxf(mz, 0.f), e3 = (__bf16)fmaxf(mw, 0.f);
        if (i < 2) { o0[i * 4 + 0] = e0; o0[i * 4 + 1] = e1; o0[i * 4 + 2] = e2; o0[i * 4 + 3] = e3; }
        else { o1[(i - 2) * 4 + 0] = e0; o1[(i - 2) * 4 + 1] = e1; o1[(i - 2) * 4 + 2] = e2; o1[(i - 2) * 4 + 3] = e3; }
      }
      __bf16* dst = &mt[(k0 + 8 * r) * 136 + C0];
      *(bf16x8*)dst = o0;
      *(bf16x8*)(dst + 8) = o1;
    }
    WAVE_LDS_SYNC();
    bf16x8 af[4];
#pragma unroll
    for (int t = 0; t < 4; ++t)
      af[t] = *(const bf16x8*)&mt[c15 * 136 + t * 32 + q * 8];
    f32x4 acc[8] = {};
#pragma unroll
    for (int nt = 0; nt < 8; ++nt)
#pragma unroll
      for (int t = 0; t < 4; ++t)
        acc[nt] = __builtin_amdgcn_mfma_f32_16x16x32_bf16(af[t], bfr[nt][t], acc[nt], 0, 0, 0);
#pragma unroll
    for (int nt = 0; nt < 8; ++nt) {
      float m4 = fmaxf(fmaxf(acc[nt][0], acc[nt][1]), fmaxf(acc[nt][2], acc[nt][3]));
      m4 = fmaxf(m4, __shfl_xor(m4, 16));
      m4 = fmaxf(m4, __shfl_xor(m4, 32));
      if ((nt >> 1) == q) {
        float bias = (nt & 1) ? bbi1 : bbi0;
        h1e[node * 160 + nt * 16 + c15] = (__bf16)fmaxf(m4 + bias, 0.f);
      }
    }
    if (lane < 32) {  // append pos (bf16) + zero pad: cols 128..159
      __bf16 v = (__bf16)0.f;
      if (lane == 0) v = (__bf16)xp;
      else if (lane == 1) v = (__bf16)yp;
      else if (lane == 2) v = (__bf16)zp;
      h1e[node * 160 + 128 + lane] = v;
    }
  }
}

// ---------------------------------------------------------------- K3: u2' = [h1|pos|0] @ W2a + b2a
__global__ __launch_bounds__(256) void mid_gemm_kernel(
    const __bf16* __restrict__ h1e, const float* __restrict__ W2a,
    const float* __restrict__ b2a, float* __restrict__ u2p) {
  __shared__ LDSA __bf16 Wt[128 * 168];  // W2a^T [n][k], k padded 131->168
  const int tid = threadIdx.x;
  uint4 z = make_uint4(0, 0, 0, 0);
  for (int idx = tid; idx < 2688; idx += 256) ((uint4*)Wt)[idx] = z;
  __syncthreads();
  for (int idx = tid; idx < 131 * 32; idx += 256) {
    int k = idx >> 5, c4 = (idx & 31) * 4;
    float4 w = *(const float4*)&W2a[k * 128 + c4];
    Wt[(c4 + 0) * 168 + k] = (__bf16)w.x;
    Wt[(c4 + 1) * 168 + k] = (__bf16)w.y;
    Wt[(c4 + 2) * 168 + k] = (__bf16)w.z;
    Wt[(c4 + 3) * 168 + k] = (__bf16)w.w;
  }
  const int wave = tid >> 6, lane = tid & 63;
  const int q = lane >> 4, c15 = lane & 15;
  float biasr[8];
#pragma unroll
  for (int nt = 0; nt < 8; ++nt) biasr[nt] = b2a[nt * 16 + c15];
  __syncthreads();
  const int row0 = (blockIdx.x * 4 + wave) * 16;
  bf16x8 af[5];
#pragma unroll
  for (int t = 0; t < 5; ++t)
    af[t] = *(const bf16x8*)(h1e + (size_t)(row0 + c15) * 160 + t * 32 + q * 8);
  f32x4 acc[8] = {};
#pragma unroll
  for (int nt = 0; nt < 8; ++nt)
#pragma unroll
    for (int t = 0; t < 5; ++t) {
      bf16x8 bf = *(const bf16x8*)&Wt[(nt * 16 + c15) * 168 + t * 32 + q * 8];
      acc[nt] = __builtin_amdgcn_mfma_f32_16x16x32_bf16(af[t], bf, acc[nt], 0, 0, 0);
    }
#pragma unroll
  for (int nt = 0; nt < 8; ++nt) {
#pragma unroll
    for (int r = 0; r < 4; ++r)
      u2p[(size_t)(row0 + q * 4 + r) * 128 + nt * 16 + c15] = acc[nt][r] + biasr[nt];
  }
}

// ---------------------------------------------------------------- K4: layer 2 + fused max pool
__global__ __launch_bounds__(256, 2) void layer2_kernel(
    const float* __restrict__ pos, const int* __restrict__ nbr,
    const float* __restrict__ u2p, const float* __restrict__ W2a,
    const float* __restrict__ W2b, const float* __restrict__ b2b,
    int* __restrict__ gG) {
  __shared__ LDSA char smem[34816];  // Wbt aliased with { mt ; proj }
  __shared__ int gpart[128];
  __bf16* Wbt = (__bf16*)smem;
  const int tid = threadIdx.x;
  for (int idx = tid; idx < 16384; idx += 256) {
    int k = idx >> 7, n = idx & 127;
    Wbt[n * 136 + k] = (__bf16)W2b[idx];
  }
  if (tid < 128) gpart[tid] = 0;
  __syncthreads();
  const int wave = tid >> 6, lane = tid & 63;
  const int q = lane >> 4, c15 = lane & 15;
  bf16x8 bfr[8][4];
#pragma unroll
  for (int nt = 0; nt < 8; ++nt)
#pragma unroll
    for (int t = 0; t < 4; ++t)
      bfr[nt][t] = *(const bf16x8*)&Wbt[(nt * 16 + c15) * 136 + t * 32 + q * 8];
  __syncthreads();  // Wbt dead
  __bf16* mt = (__bf16*)smem + wave * 2176;
  float* proj = (float*)(smem + 17408) + wave * 128;
  const int cb = lane & 7, k0 = lane >> 3, C0 = cb * 16;
  const int c2 = lane * 2;
  const float r0a = W2a[16384 + c2], r0b = W2a[16384 + c2 + 1];
  const float r1a = W2a[16512 + c2], r1b = W2a[16512 + c2 + 1];
  const float r2a = W2a[16640 + c2], r2b = W2a[16640 + c2 + 1];
  const float bbi0 = b2b[q * 32 + c15], bbi1 = b2b[q * 32 + 16 + c15];
  const int blk = blockIdx.x, b = blk >> 5;
  const size_t bbase = (size_t)b * 2048;
  const int p0 = (blk & 31) * 64 + wave * 16;
  for (int it = 0; it < 16; ++it) {
    const size_t node = bbase + p0 + it;
    const float* pp = pos + node * 3;
    const float xp = pp[0], yp = pp[1], zp = pp[2];
    const int j0 = nbr[node * 16 + k0];
    const int j1 = nbr[node * 16 + k0 + 8];
    const float* ur0 = u2p + (size_t)(bbase + j0) * 128 + C0;
    const float* ur1 = u2p + (size_t)(bbase + j1) * 128 + C0;
    float4 u0[4], u1[4];
#pragma unroll
    for (int i = 0; i < 4; ++i) { u0[i] = *(const float4*)&ur0[4 * i]; u1[i] = *(const float4*)&ur1[4 * i]; }
    float v0 = fmaf(xp, r0a, fmaf(yp, r1a, zp * r2a));
    float v1 = fmaf(xp, r0b, fmaf(yp, r1b, zp * r2b));
    *(float2*)&proj[c2] = make_float2(v0, v1);
    WAVE_LDS_SYNC();
    float4 pj[4];
#pragma unroll
    for (int i = 0; i < 4; ++i) pj[i] = *(const float4*)&proj[C0 + 4 * i];
#pragma unroll
    for (int r = 0; r < 2; ++r) {
      bf16x8 o0, o1;
#pragma unroll
      for (int i = 0; i < 4; ++i) {
        float4 uu = r ? u1[i] : u0[i];
        __bf16 e0 = (__bf16)fmaxf(uu.x - pj[i].x, 0.f);
        __bf16 e1 = (__bf16)fmaxf(uu.y - pj[i].y, 0.f);
        __bf16 e2 = (__bf16)fmaxf(uu.z - pj[i].z, 0.f);
        __bf16 e3 = (__bf16)fmaxf(uu.w - pj[i].w, 0.f);
        if (i < 2) { o0[i * 4 + 0] = e0; o0[i * 4 + 1] = e1; o0[i * 4 + 2] = e2; o0[i * 4 + 3] = e3; }
        else { o1[(i - 2) * 4 + 0] = e0; o1[(i - 2) * 4 + 1] = e1; o1[(i - 2) * 4 + 2] = e2; o1[(i - 2) * 4 + 3] = e3; }
      }
      __bf16* dst = &mt[(k0 + 8 * r) * 136 + C0];
      *(bf16x8*)dst = o0;
      *(bf16x8*)(dst + 8) = o1;
    }
    WAVE_LDS_SYNC();
    bf16x8 af[4];
#pragma unroll
    for (int t = 0; t < 4; ++t)
      af[t] = *(const bf16x8*)&mt[c15 * 136 + t * 32 + q * 8];
    f32x4 acc[8] = {};
#pragma unroll
    for (int nt = 0; nt < 8; ++nt)
#pragma unroll
      for (int t = 0; t < 4; ++t)
        acc[nt] = __builtin_amdgcn_mfma_f32_16x16x32_bf16(af[t], bfr[nt][t], acc[nt], 0, 0, 0);
#pragma unroll
    for (int nt = 0; nt < 8; ++nt) {
      float m4 = fmaxf(fmaxf(acc[nt][0], acc[nt][1]), fmaxf(acc[nt][2], acc[nt][3]));
      m4 = fmaxf(m4, __shfl_xor(m4, 16));
      m4 = fmaxf(m4, __shfl_xor(m4, 32));
      if ((nt >> 1) == q) {
        float bias = (nt & 1) ? bbi1 : bbi0;
        float h = fmaxf(m4 + bias, 0.f);
        atomicMax(&gpart[nt * 16 + c15], __float_as_int(h));  // h>=0: int-max == float-max
      }
    }
  }
  __syncthreads();
  if (tid < 128) atomicMax(&gG[b * 128 + tid], gpart[tid]);
}

// ---------------------------------------------------------------- K5: classifier
__global__ __launch_bounds__(64) void cls_kernel(const int* __restrict__ gG,
                                                 const float* __restrict__ Wc,
                                                 const float* __restrict__ bc,
                                                 float* __restrict__ out) {
  const int b = blockIdx.x, lane = threadIdx.x;
  float g1 = __int_as_float(gG[b * 128 + lane]);
  float g2 = __int_as_float(gG[b * 128 + 64 + lane]);
  float accn[10];
#pragma unroll
  for (int n = 0; n < 10; ++n)
    accn[n] = g1 * Wc[lane * 10 + n] + g2 * Wc[(64 + lane) * 10 + n];
#pragma unroll
  for (int n = 0; n < 10; ++n) {
#pragma unroll
    for (int off = 32; off >= 1; off >>= 1) accn[n] += __shfl_xor(accn[n], off);
  }
  if (lane == 0) {
#pragma unroll
    for (int n = 0; n < 10; ++n) out[b * 10 + n] = accn[n] + bc[n];
  }
}

// ---------------------------------------------------------------- launcher
extern "C" void kernel_launch(void* const* d_in, const int* in_sizes, int n_in,
                              void* d_out, int out_size, void* d_ws, size_t ws_size,
                              hipStream_t stream) {
  const float* pos = (const float*)d_in[0];
  // d_in[1] = batch (unused: graphs are equal-size, sorted)
  const float* W1a = (const float*)d_in[2];
  const float* b1a = (const float*)d_in[3];
  const float* W1b = (const float*)d_in[4];
  const float* b1b = (const float*)d_in[5];
  const float* W2a = (const float*)d_in[6];
  const float* b2a = (const float*)d_in[7];
  const float* W2b = (const float*)d_in[8];
  const float* b2b = (const float*)d_in[9];
  const float* Wc  = (const float*)d_in[10];
  const float* bc  = (const float*)d_in[11];

  char* ws = (char*)d_ws;
  int*    nbr = (int*)ws;                          //  4 MB : [65536][16]
  __bf16* h1e = (__bf16*)(ws + 4194304);           // 20 MB : [65536][160]
  float*  u2p = (float*)(ws + 25165824);           // 32 MB : [65536][128]
  int*    gG  = (int*)(ws + 58720256);             // 16 KB : [32][128]
  float*  out = (float*)d_out;

  hipMemsetAsync(gG, 0, 32 * 128 * sizeof(int), stream);  // relu>=0, bits(0)==0.0f
  knn_kernel<<<1024, 512, 0, stream>>>(pos, nbr);
  layer1_kernel<<<1024, 256, 0, stream>>>(pos, nbr, W1a, b1a, W1b, b1b, h1e);
  mid_gemm_kernel<<<1024, 256, 0, stream>>>(h1e, W2a, b2a, u2p);
  layer2_kernel<<<1024, 256, 0, stream>>>(pos, nbr, u2p, W2a, W2b, b2b, gG);
  cls_kernel<<<32, 64, 0, stream>>>(gG, Wc, bc, out);
}

// Round 4
// 350.832 us; speedup vs baseline: 2.5116x; 1.2508x over previous
//
#include <hip/hip_runtime.h>

// PointNet on MI355X. B=32, P=2048, K=16, NHID=128, NCLS=10.
//   K1 knn      : brute-force d2; per-lane streaming float top-3; SET-based selection (downstream is
//                 max over K => order-invariant): 32-step ballot binary search for the 16th-smallest
//                 monotone key V, then ballot-ranked scatter of {key<V} plus (16-count) of {key==V}.
//                 Exact rare fallback (any lane's k3 < V => its unbuffered 4th might belong) to the
//                 old 16-round u64 pop-with-refill.
//   K2 layer1   : msg = relu(pos_j*(A+B) + (b1a - pos_p*B)); v = msg @ W1b (MFMA); h1 = relu(max_k v + b1b)
//                 Wave-private LDS (no block barriers in loop); nbr/pos prefetched one iter ahead.
//   K3 midgemm  : u2' = [h1|pos|0] @ W2a(all 131 rows) + b2a -> bf16. 4 row-tiles/block (staging amortized).
//   K4 layer2   : msg = relu(u2'[j] - pos_p*R); v = msg @ W2b (MFMA); fused global max pool.
//                 u2p gather is bf16 (256 MB->... 16 MB footprint) + XCD swizzle: each graph's 32 blocks
//                 on one XCD so the graph's 0.5 MB u2p slice stays L2-resident.
//   K5 cls      : out = g @ Wc + bc
// MFMA layouts per verified m89/m97 mappings.

typedef __bf16 bf16x8 __attribute__((ext_vector_type(8)));
typedef float  f32x4  __attribute__((ext_vector_type(4)));

#define LDSA __attribute__((aligned(16)))
#define WAVE_LDS_SYNC() __asm__ volatile("s_waitcnt lgkmcnt(0)" ::: "memory")

// ---------------------------------------------------------------- K1: KNN
__global__ __launch_bounds__(512, 4) void knn_kernel(const float* __restrict__ pos,
                                                     int* __restrict__ nbr) {
  __shared__ LDSA float4 P4[2048];  // {x,y,z,|p|^2}
  const int blk = blockIdx.x;
  const int b = blk >> 5;
  const int tid = threadIdx.x;
  const size_t bbase = (size_t)b * 2048;
  for (int idx = tid; idx < 2048; idx += 512) {
    const float* pp = pos + (bbase + idx) * 3;
    float x = pp[0], y = pp[1], z = pp[2];
    P4[idx] = make_float4(x, y, z, fmaf(z, z, fmaf(y, y, x * x)));
  }
  __syncthreads();
  const int wave = tid >> 6, lane = tid & 63;
  const int p0 = (blk & 31) * 64 + wave * 8;   // 8 points per wave
  const unsigned long long below = (1ull << lane) - 1ull;
  const float FINF = __uint_as_float(0x7F800000u);
  for (int it = 0; it < 8; ++it) {
    const int pl = p0 + it;
    const float4 P = P4[pl];
    // ---- phase 1: streaming per-lane sorted top-3 (float compares) ----
    float m1 = FINF, m2 = FINF, m3 = FINF;
    unsigned s1 = 0, s2 = 0, s3 = 0;
#pragma unroll 8
    for (int i = 0; i < 32; ++i) {
      int c = lane + (i << 6);
      float4 Q = P4[c];
      float d2 = (P.w + Q.w) - 2.0f * fmaf(P.z, Q.z, fmaf(P.y, Q.y, P.x * Q.x));
      bool c3 = d2 < m3, c2 = d2 < m2, c1 = d2 < m1;
      m3 = c2 ? m2 : (c3 ? d2 : m3);  s3 = c2 ? s2 : (c3 ? (unsigned)c : s3);
      m2 = c1 ? m1 : (c2 ? d2 : m2);  s2 = c1 ? s1 : (c2 ? (unsigned)c : s2);
      m1 = c1 ? d2 : m1;              s1 = c1 ? (unsigned)c : s1;
    }
    // ---- monotone float->u32 keys ----
    unsigned k1 = __float_as_uint(m1); k1 = ((int)k1 < 0) ? ~k1 : (k1 | 0x80000000u);
    unsigned k2 = __float_as_uint(m2); k2 = ((int)k2 < 0) ? ~k2 : (k2 | 0x80000000u);
    unsigned k3 = __float_as_uint(m3); k3 = ((int)k3 < 0) ? ~k3 : (k3 | 0x80000000u);
    // ---- phase 2: binary search for V = 16th smallest buffered key ----
    unsigned v = 0;
#pragma unroll
    for (int bit = 31; bit >= 0; --bit) {
      unsigned t = v | (1u << bit);
      int cnt = __popcll(__ballot(k1 < t)) + __popcll(__ballot(k2 < t)) +
                __popcll(__ballot(k3 < t));
      if (cnt < 16) v = t;  // keep invariant count(< v) < 16; final v = 16th smallest
    }
    const unsigned V = v;
    const long long outbase = ((long long)bbase + pl) * 16;
    if (__any(k3 < V)) {
      // ---- exact fallback (~11% of points): a lane may hold >3 of the top-16 ----
      unsigned long long K1 = ((unsigned long long)k1 << 32) | s1;
      unsigned long long K2 = ((unsigned long long)k2 << 32) | s2;
      unsigned long long K3 = ((unsigned long long)k3 << 32) | s3;
      unsigned long long lastk = 0;
      for (int r = 0; r < 16; ++r) {
        unsigned long long k = K1, kmin = K1;
#pragma unroll
        for (int off = 1; off < 64; off <<= 1) {
          unsigned long long o = __shfl_xor(kmin, off);
          kmin = (o < kmin) ? o : kmin;
        }
        if (lane == r) nbr[outbase + r] = (int)(kmin & 0xFFFFFFFFull);
        if (k == kmin) { lastk = k; K1 = K2; K2 = K3; K3 = ~0ull; }
        if (r < 15 && __any(K1 == ~0ull)) {
          if (K1 == ~0ull) {
            unsigned long long best = ~0ull;
            for (int i = 0; i < 32; ++i) {
              int c = lane + (i << 6);
              float4 Q = P4[c];
              float d2 = (P.w + Q.w) - 2.0f * fmaf(P.z, Q.z, fmaf(P.y, Q.y, P.x * Q.x));
              unsigned u = __float_as_uint(d2);
              u = ((int)u < 0) ? ~u : (u | 0x80000000u);
              unsigned long long kc = ((unsigned long long)u << 32) | (unsigned)c;
              bool ok = (kc > lastk) & (kc < best);
              best = ok ? kc : best;
            }
            K1 = best;
          }
        }
      }
    } else {
      // ---- set emission: all keys < V, plus (16 - count) of the == V ties ----
      unsigned long long L1 = __ballot(k1 < V), L2 = __ballot(k2 < V), L3 = __ballot(k3 < V);
      unsigned long long E1 = __ballot(k1 == V), E2 = __ballot(k2 == V), E3 = __ballot(k3 == V);
      int cA = __popcll(L1), cB = cA + __popcll(L2), cT = cB + __popcll(L3);
      int eA = __popcll(E1), eB = eA + __popcll(E2);
      {
        bool lt = k1 < V, eq = k1 == V;
        int plt = __popcll(L1 & below);
        int peq = cT + __popcll(E1 & below);
        int p = lt ? plt : peq;
        if (lt || (eq && peq < 16)) nbr[outbase + p] = (int)s1;
      }
      {
        bool lt = k2 < V, eq = k2 == V;
        int plt = cA + __popcll(L2 & below);
        int peq = cT + eA + __popcll(E2 & below);
        int p = lt ? plt : peq;
        if (lt || (eq && peq < 16)) nbr[outbase + p] = (int)s2;
      }
      {
        bool lt = k3 < V, eq = k3 == V;
        int plt = cB + __popcll(L3 & below);
        int peq = cT + eB + __popcll(E3 & below);
        int p = lt ? plt : peq;
        if (lt || (eq && peq < 16)) nbr[outbase + p] = (int)s3;
      }
    }
  }
}

// ---------------------------------------------------------------- K2: layer 1
__global__ __launch_bounds__(256, 2) void layer1_kernel(
    const float* __restrict__ pos, const int* __restrict__ nbr,
    const float* __restrict__ W1a, const float* __restrict__ b1a,
    const float* __restrict__ W1b, const float* __restrict__ b1b,
    __bf16* __restrict__ h1e) {
  __shared__ LDSA char smem[34816];  // Wbt aliased with { mt ; base }
  __bf16* Wbt = (__bf16*)smem;
  const int tid = threadIdx.x;
  for (int idx = tid; idx < 16384; idx += 256) {
    int k = idx >> 7, n = idx & 127;
    Wbt[n * 136 + k] = (__bf16)W1b[idx];
  }
  __syncthreads();
  const int wave = tid >> 6, lane = tid & 63;
  const int q = lane >> 4, c15 = lane & 15;
  bf16x8 bfr[8][4];  // W1b^T fragments resident (128 VGPRs)
#pragma unroll
  for (int nt = 0; nt < 8; ++nt)
#pragma unroll
    for (int t = 0; t < 4; ++t)
      bfr[nt][t] = *(const bf16x8*)&Wbt[(nt * 16 + c15) * 136 + t * 32 + q * 8];
  __syncthreads();  // Wbt dead: space reused for mt/base
  __bf16* mt = (__bf16*)smem + wave * 2176;          // [16 rows][136]
  float* base = (float*)(smem + 17408) + wave * 128;
  const int cb = lane & 7, k0 = lane >> 3, C0 = cb * 16;
  float4 s0h[4], s1h[4], s2h[4];  // (A+B) rows for this lane's 16 channels
#pragma unroll
  for (int i = 0; i < 4; ++i) {
    float4 a0 = *(const float4*)&W1a[      C0 + 4 * i], r0 = *(const float4*)&W1a[384 + C0 + 4 * i];
    float4 a1 = *(const float4*)&W1a[128 + C0 + 4 * i], r1 = *(const float4*)&W1a[512 + C0 + 4 * i];
    float4 a2 = *(const float4*)&W1a[256 + C0 + 4 * i], r2 = *(const float4*)&W1a[640 + C0 + 4 * i];
    s0h[i] = make_float4(a0.x + r0.x, a0.y + r0.y, a0.z + r0.z, a0.w + r0.w);
    s1h[i] = make_float4(a1.x + r1.x, a1.y + r1.y, a1.z + r1.z, a1.w + r1.w);
    s2h[i] = make_float4(a2.x + r2.x, a2.y + r2.y, a2.z + r2.z, a2.w + r2.w);
  }
  const int c2 = lane * 2;
  const float br0a = W1a[384 + c2], br0b = W1a[384 + c2 + 1];
  const float br1a = W1a[512 + c2], br1b = W1a[512 + c2 + 1];
  const float br2a = W1a[640 + c2], br2b = W1a[640 + c2 + 1];
  const float ba0 = b1a[c2], ba1 = b1a[c2 + 1];
  const float bbi0 = b1b[q * 32 + c15], bbi1 = b1b[q * 32 + 16 + c15];
  const int blk = blockIdx.x, b = blk >> 5;
  const size_t bbase = (size_t)b * 2048;
  const int p0 = (blk & 31) * 64 + wave * 16;
  size_t node = bbase + p0;
  // prefetch it=0
  int j0 = nbr[node * 16 + k0];
  int j1 = nbr[node * 16 + k0 + 8];
  float px = pos[node * 3], py = pos[node * 3 + 1], pz = pos[node * 3 + 2];
  for (int it = 0; it < 16; ++it) {
    const int j0c = j0, j1c = j1;
    const float xp = px, yp = py, zp = pz;
    const size_t nodec = node;
    if (it < 15) {  // prefetch next iteration's indices + own pos
      node = nodec + 1;
      j0 = nbr[node * 16 + k0];
      j1 = nbr[node * 16 + k0 + 8];
      px = pos[node * 3]; py = pos[node * 3 + 1]; pz = pos[node * 3 + 2];
    }
    const float* pj0 = pos + (bbase + j0c) * 3;
    const float* pj1 = pos + (bbase + j1c) * 3;
    const float xa = pj0[0], ya = pj0[1], za = pj0[2];
    const float xb = pj1[0], yb = pj1[1], zb = pj1[2];
    float v0 = ba0 - fmaf(xp, br0a, fmaf(yp, br1a, zp * br2a));
    float v1 = ba1 - fmaf(xp, br0b, fmaf(yp, br1b, zp * br2b));
    *(float2*)&base[c2] = make_float2(v0, v1);
    WAVE_LDS_SYNC();
    float4 bb[4];
#pragma unroll
    for (int i = 0; i < 4; ++i) bb[i] = *(const float4*)&base[C0 + 4 * i];
#pragma unroll
    for (int r = 0; r < 2; ++r) {
      const float xj = r ? xb : xa, yj = r ? yb : ya, zj = r ? zb : za;
      bf16x8 o0, o1;
#pragma unroll
      for (int i = 0; i < 4; ++i) {
        float mx = fmaf(xj, s0h[i].x, fmaf(yj, s1h[i].x, fmaf(zj, s2h[i].x, bb[i].x)));
        float my = fmaf(xj, s0h[i].y, fmaf(yj, s1h[i].y, fmaf(zj, s2h[i].y, bb[i].y)));
        float mz = fmaf(xj, s0h[i].z, fmaf(yj, s1h[i].z, fmaf(zj, s2h[i].z, bb[i].z)));
        float mw = fmaf(xj, s0h[i].w, fmaf(yj, s1h[i].w, fmaf(zj, s2h[i].w, bb[i].w)));
        __bf16 e0 = (__bf16)fmaxf(mx, 0.f), e1 = (__bf16)fmaxf(my, 0.f);
        __bf16 e2 = (__bf16)fmaxf(mz, 0.f), e3 = (__bf16)fmaxf(mw, 0.f);
        if (i < 2) { o0[i * 4 + 0] = e0; o0[i * 4 + 1] = e1; o0[i * 4 + 2] = e2; o0[i * 4 + 3] = e3; }
        else { o1[(i - 2) * 4 + 0] = e0; o1[(i - 2) * 4 + 1] = e1; o1[(i - 2) * 4 + 2] = e2; o1[(i - 2) * 4 + 3] = e3; }
      }
      __bf16* dst = &mt[(k0 + 8 * r) * 136 + C0];
      *(bf16x8*)dst = o0;
      *(bf16x8*)(dst + 8) = o1;
    }
    WAVE_LDS_SYNC();
    bf16x8 af[4];
#pragma unroll
    for (int t = 0; t < 4; ++t)
      af[t] = *(const bf16x8*)&mt[c15 * 136 + t * 32 + q * 8];
    f32x4 acc[8] = {};
#pragma unroll
    for (int nt = 0; nt < 8; ++nt)
#pragma unroll
      for (int t = 0; t < 4; ++t)
        acc[nt] = __builtin_amdgcn_mfma_f32_16x16x32_bf16(af[t], bfr[nt][t], acc[nt], 0, 0, 0);
#pragma unroll
    for (int nt = 0; nt < 8; ++nt) {
      float m4 = fmaxf(fmaxf(acc[nt][0], acc[nt][1]), fmaxf(acc[nt][2], acc[nt][3]));
      m4 = fmaxf(m4, __shfl_xor(m4, 16));
      m4 = fmaxf(m4, __shfl_xor(m4, 32));
      if ((nt >> 1) == q) {
        float bias = (nt & 1) ? bbi1 : bbi0;
        h1e[nodec * 160 + nt * 16 + c15] = (__bf16)fmaxf(m4 + bias, 0.f);
      }
    }
    if (lane < 32) {  // append pos (bf16) + zero pad: cols 128..159
      __bf16 v = (__bf16)0.f;
      if (lane == 0) v = (__bf16)xp;
      else if (lane == 1) v = (__bf16)yp;
      else if (lane == 2) v = (__bf16)zp;
      h1e[nodec * 160 + 128 + lane] = v;
    }
  }
}

// ---------------------------------------------------------------- K3: u2' = [h1|pos|0] @ W2a + b2a (bf16 out)
__global__ __launch_bounds__(256) void mid_gemm_kernel(
    const __bf16* __restrict__ h1e, const float* __restrict__ W2a,
    const float* __restrict__ b2a, __bf16* __restrict__ u2p) {
  __shared__ LDSA __bf16 Wt[128 * 168];  // W2a^T [n][k], k padded 131->168
  const int tid = threadIdx.x;
  uint4 z = make_uint4(0, 0, 0, 0);
  for (int idx = tid; idx < 2688; idx += 256) ((uint4*)Wt)[idx] = z;
  __syncthreads();
  for (int idx = tid; idx < 131 * 32; idx += 256) {
    int k = idx >> 5, c4 = (idx & 31) * 4;
    float4 w = *(const float4*)&W2a[k * 128 + c4];
    Wt[(c4 + 0) * 168 + k] = (__bf16)w.x;
    Wt[(c4 + 1) * 168 + k] = (__bf16)w.y;
    Wt[(c4 + 2) * 168 + k] = (__bf16)w.z;
    Wt[(c4 + 3) * 168 + k] = (__bf16)w.w;
  }
  const int wave = tid >> 6, lane = tid & 63;
  const int q = lane >> 4, c15 = lane & 15;
  float biasr[8];
#pragma unroll
  for (int nt = 0; nt < 8; ++nt) biasr[nt] = b2a[nt * 16 + c15];
  __syncthreads();
  for (int tile = 0; tile < 4; ++tile) {  // 4 row-tiles/block: staging amortized
    const int row0 = blockIdx.x * 256 + tile * 64 + wave * 16;
    bf16x8 af[5];
#pragma unroll
    for (int t = 0; t < 5; ++t)
      af[t] = *(const bf16x8*)(h1e + (size_t)(row0 + c15) * 160 + t * 32 + q * 8);
    f32x4 acc[8] = {};
#pragma unroll
    for (int nt = 0; nt < 8; ++nt)
#pragma unroll
      for (int t = 0; t < 5; ++t) {
        bf16x8 bf = *(const bf16x8*)&Wt[(nt * 16 + c15) * 168 + t * 32 + q * 8];
        acc[nt] = __builtin_amdgcn_mfma_f32_16x16x32_bf16(af[t], bf, acc[nt], 0, 0, 0);
      }
#pragma unroll
    for (int nt = 0; nt < 8; ++nt) {
#pragma unroll
      for (int r = 0; r < 4; ++r)
        u2p[(size_t)(row0 + q * 4 + r) * 128 + nt * 16 + c15] = (__bf16)(acc[nt][r] + biasr[nt]);
    }
  }
}

// ---------------------------------------------------------------- K4: layer 2 + fused max pool
__global__ __launch_bounds__(256, 2) void layer2_kernel(
    const float* __restrict__ pos, const int* __restrict__ nbr,
    const __bf16* __restrict__ u2p, const float* __restrict__ W2a,
    const float* __restrict__ W2b, const float* __restrict__ b2b,
    int* __restrict__ gG) {
  __shared__ LDSA char smem[34816];  // Wbt aliased with { mt ; proj }
  __shared__ int gpart[128];
  __bf16* Wbt = (__bf16*)smem;
  const int tid = threadIdx.x;
  for (int idx = tid; idx < 16384; idx += 256) {
    int k = idx >> 7, n = idx & 127;
    Wbt[n * 136 + k] = (__bf16)W2b[idx];
  }
  if (tid < 128) gpart[tid] = 0;
  __syncthreads();
  const int wave = tid >> 6, lane = tid & 63;
  const int q = lane >> 4, c15 = lane & 15;
  bf16x8 bfr[8][4];
#pragma unroll
  for (int nt = 0; nt < 8; ++nt)
#pragma unroll
    for (int t = 0; t < 4; ++t)
      bfr[nt][t] = *(const bf16x8*)&Wbt[(nt * 16 + c15) * 136 + t * 32 + q * 8];
  __syncthreads();  // Wbt dead
  __bf16* mt = (__bf16*)smem + wave * 2176;
  float* proj = (float*)(smem + 17408) + wave * 128;
  const int cb = lane & 7, k0 = lane >> 3, C0 = cb * 16;
  const int c2 = lane * 2;
  const float r0a = W2a[16384 + c2], r0b = W2a[16384 + c2 + 1];
  const float r1a = W2a[16512 + c2], r1b = W2a[16512 + c2 + 1];
  const float r2a = W2a[16640 + c2], r2b = W2a[16640 + c2 + 1];
  const float bbi0 = b2b[q * 32 + c15], bbi1 = b2b[q * 32 + 16 + c15];
  // XCD swizzle: graph g's 32 blocks -> one XCD (blk%8 assumed XCD round-robin; perf-only)
  const int lb = blockIdx.x;
  const int xcd = lb & 7, slot = lb >> 3;
  const int b = xcd + 8 * (slot >> 5);
  const int bi = slot & 31;
  const size_t bbase = (size_t)b * 2048;
  const int p0 = bi * 64 + wave * 16;
  size_t node = bbase + p0;
  int j0 = nbr[node * 16 + k0];
  int j1 = nbr[node * 16 + k0 + 8];
  float px = pos[node * 3], py = pos[node * 3 + 1], pz = pos[node * 3 + 2];
  for (int it = 0; it < 16; ++it) {
    const int j0c = j0, j1c = j1;
    const float xp = px, yp = py, zp = pz;
    const size_t nodec = node;
    if (it < 15) {
      node = nodec + 1;
      j0 = nbr[node * 16 + k0];
      j1 = nbr[node * 16 + k0 + 8];
      px = pos[node * 3]; py = pos[node * 3 + 1]; pz = pos[node * 3 + 2];
    }
    const __bf16* ur0 = u2p + (size_t)(bbase + j0c) * 128 + C0;
    const __bf16* ur1 = u2p + (size_t)(bbase + j1c) * 128 + C0;
    bf16x8 ua0 = *(const bf16x8*)ur0, ua1 = *(const bf16x8*)(ur0 + 8);
    bf16x8 ub0 = *(const bf16x8*)ur1, ub1 = *(const bf16x8*)(ur1 + 8);
    float v0 = fmaf(xp, r0a, fmaf(yp, r1a, zp * r2a));
    float v1 = fmaf(xp, r0b, fmaf(yp, r1b, zp * r2b));
    *(float2*)&proj[c2] = make_float2(v0, v1);
    WAVE_LDS_SYNC();
    float pj[16];
#pragma unroll
    for (int i = 0; i < 4; ++i) *(float4*)&pj[4 * i] = *(const float4*)&proj[C0 + 4 * i];
#pragma unroll
    for (int r = 0; r < 2; ++r) {
      bf16x8 u0 = r ? ub0 : ua0, u1 = r ? ub1 : ua1;
      bf16x8 o0, o1;
#pragma unroll
      for (int e = 0; e < 8; ++e) o0[e] = (__bf16)fmaxf((float)u0[e] - pj[e], 0.f);
#pragma unroll
      for (int e = 0; e < 8; ++e) o1[e] = (__bf16)fmaxf((float)u1[e] - pj[8 + e], 0.f);
      __bf16* dst = &mt[(k0 + 8 * r) * 136 + C0];
      *(bf16x8*)dst = o0;
      *(bf16x8*)(dst + 8) = o1;
    }
    WAVE_LDS_SYNC();
    bf16x8 af[4];
#pragma unroll
    for (int t = 0; t < 4; ++t)
      af[t] = *(const bf16x8*)&mt[c15 * 136 + t * 32 + q * 8];
    f32x4 acc[8] = {};
#pragma unroll
    for (int nt = 0; nt < 8; ++nt)
#pragma unroll
      for (int t = 0; t < 4; ++t)
        acc[nt] = __builtin_amdgcn_mfma_f32_16x16x32_bf16(af[t], bfr[nt][t], acc[nt], 0, 0, 0);
#pragma unroll
    for (int nt = 0; nt < 8; ++nt) {
      float m4 = fmaxf(fmaxf(acc[nt][0], acc[nt][1]), fmaxf(acc[nt][2], acc[nt][3]));
      m4 = fmaxf(m4, __shfl_xor(m4, 16));
      m4 = fmaxf(m4, __shfl_xor(m4, 32));
      if ((nt >> 1) == q) {
        float bias = (nt & 1) ? bbi1 : bbi0;
        float h = fmaxf(m4 + bias, 0.f);
        atomicMax(&gpart[nt * 16 + c15], __float_as_int(h));  // h>=0: int-max == float-max
      }
    }
  }
  __syncthreads();
  if (tid < 128) atomicMax(&gG[b * 128 + tid], gpart[tid]);
}

// ---------------------------------------------------------------- K5: classifier
__global__ __launch_bounds__(64) void cls_kernel(const int* __restrict__ gG,
                                                 const float* __restrict__ Wc,
                                                 const float* __restrict__ bc,
                                                 float* __restrict__ out) {
  const int b = blockIdx.x, lane = threadIdx.x;
  float g1 = __int_as_float(gG[b * 128 + lane]);
  float g2 = __int_as_float(gG[b * 128 + 64 + lane]);
  float accn[10];
#pragma unroll
  for (int n = 0; n < 10; ++n)
    accn[n] = g1 * Wc[lane * 10 + n] + g2 * Wc[(64 + lane) * 10 + n];
#pragma unroll
  for (int n = 0; n < 10; ++n) {
#pragma unroll
    for (int off = 32; off >= 1; off >>= 1) accn[n] += __shfl_xor(accn[n], off);
  }
  if (lane == 0) {
#pragma unroll
    for (int n = 0; n < 10; ++n) out[b * 10 + n] = accn[n] + bc[n];
  }
}

// ---------------------------------------------------------------- launcher
extern "C" void kernel_launch(void* const* d_in, const int* in_sizes, int n_in,
                              void* d_out, int out_size, void* d_ws, size_t ws_size,
                              hipStream_t stream) {
  const float* pos = (const float*)d_in[0];
  // d_in[1] = batch (unused: graphs are equal-size, sorted)
  const float* W1a = (const float*)d_in[2];
  const float* b1a = (const float*)d_in[3];
  const float* W1b = (const float*)d_in[4];
  const float* b1b = (const float*)d_in[5];
  const float* W2a = (const float*)d_in[6];
  const float* b2a = (const float*)d_in[7];
  const float* W2b = (const float*)d_in[8];
  const float* b2b = (const float*)d_in[9];
  const float* Wc  = (const float*)d_in[10];
  const float* bc  = (const float*)d_in[11];

  char* ws = (char*)d_ws;
  int*    nbr = (int*)ws;                          //  4 MB : [65536][16]
  __bf16* h1e = (__bf16*)(ws + 4194304);           // 20 MB : [65536][160]
  __bf16* u2p = (__bf16*)(ws + 25165824);          // 16 MB : [65536][128] bf16
  int*    gG  = (int*)(ws + 41943040);             // 16 KB : [32][128]
  float*  out = (float*)d_out;

  hipMemsetAsync(gG, 0, 32 * 128 * sizeof(int), stream);  // relu>=0, bits(0)==0.0f
  knn_kernel<<<1024, 512, 0, stream>>>(pos, nbr);
  layer1_kernel<<<1024, 256, 0, stream>>>(pos, nbr, W1a, b1a, W1b, b1b, h1e);
  mid_gemm_kernel<<<256, 256, 0, stream>>>(h1e, W2a, b2a, u2p);
  layer2_kernel<<<1024, 256, 0, stream>>>(pos, nbr, u2p, W2a, W2b, b2b, gG);
  cls_kernel<<<32, 64, 0, stream>>>(gG, Wc, bc, out);
}